// Round 5
// baseline (164.203 us; speedup 1.0000x reference)
//
#include <hip/hip_runtime.h>
#include <cstdint>
#include <cstddef>

// out[64,197,768] = concat(cls, patchify(images[64,3,224,224]) @ W^T + b)
// R5: single fused GEMM pass, barrier-light K-loop.
//  - A-tile (64 rows x 768 k, bf16) resident in LDS, staged in two K-halves
//    (48.5 KB -> 3 blocks/CU co-residency). Patchify gather fused into stage.
//  - B-fragments read DIRECTLY from L2-resident bf16 W (no LDS, no barriers
//    in the 12-step inner K-loop). Only 3 barriers per block total.
//  - Block = 64m x 256n, 512 threads (8 waves of 32m x 64n). Grid 588.
#define MTOT 12544
#define KTOT 768
#define PITCH 388   // LDS row pitch (elems): 776 B == 8 mod 128 -> 2-way max conflicts

typedef float  f32x4  __attribute__((ext_vector_type(4)));
typedef __bf16 bf16x8 __attribute__((ext_vector_type(8)));

// ---------------- Prep: W fp32->bf16 + cls rows (tiny) ----------------
#define W_BLOCKS   288   // 768*768/8/256
#define CLS_BLOCKS 48    // 64*768/4/256

__global__ __launch_bounds__(256) void prep_kernel(
    const float* __restrict__ Wm, const float* __restrict__ cls,
    float* __restrict__ out, __bf16* __restrict__ Wb) {
  const int bid = blockIdx.x, tid = threadIdx.x;
  if (bid < W_BLOCKS) {
    const size_t q = (size_t)bid * 256 + tid;
    const float4 v0 = *(const float4*)(Wm + q * 8);
    const float4 v1 = *(const float4*)(Wm + q * 8 + 4);
    bf16x8 o;
    o[0]=(__bf16)v0.x; o[1]=(__bf16)v0.y; o[2]=(__bf16)v0.z; o[3]=(__bf16)v0.w;
    o[4]=(__bf16)v1.x; o[5]=(__bf16)v1.y; o[6]=(__bf16)v1.z; o[7]=(__bf16)v1.w;
    *(bf16x8*)(Wb + q * 8) = o;
  } else {
    const int t  = (bid - W_BLOCKS) * 256 + tid;
    const int bb = t / 192;
    const int r  = t - bb * 192;
    *(float4*)(out + (size_t)bb * 197 * 768 + r * 4) = *(const float4*)(cls + r * 4);
  }
}

// ---------------- Fused patchify + GEMM ----------------
__device__ __forceinline__ void cvt_store(__bf16* dst, const f32x4 a, const f32x4 b) {
  bf16x8 o;
  o[0]=(__bf16)a[0]; o[1]=(__bf16)a[1]; o[2]=(__bf16)a[2]; o[3]=(__bf16)a[3];
  o[4]=(__bf16)b[0]; o[5]=(__bf16)b[1]; o[6]=(__bf16)b[2]; o[7]=(__bf16)b[3];
  *(bf16x8*)dst = o;
}

__global__ __launch_bounds__(512) void gemm_kernel(
    const float* __restrict__ images, const __bf16* __restrict__ Wb,
    const float* __restrict__ bias, float* __restrict__ out) {
  __shared__ __bf16 As[64 * PITCH];   // 49,664 B -> 3 blocks/CU

  const int tid  = threadIdx.x;
  const int bx   = blockIdx.x;
  const int mblk = bx / 3, nblk = bx - mblk * 3;
  const int m0 = mblk * 64, n0 = nblk * 256;
  const int w = tid >> 6, lane = tid & 63;
  const int mg = w & 1;        // m-half (32 rows)
  const int ng = w >> 1;       // n-quarter (64 cols)
  const int lrow = lane & 15, lq = lane >> 4;

  // A-stage addressing: thread owns image row arow = tid&63; covers
  // k-segments s = w + 8*i (i<3) of 16 elems within the current K-half.
  const int arow = tid & 63;
  const int m  = m0 + arow;
  const int bb = m / 196, p = m - bb * 196;
  const int pi = p / 14,  pj = p - pi * 14;
  const size_t ibase = ((size_t)(bb * 3) * 224 + (size_t)(pi * 16)) * 224 + pj * 16;

  f32x4 acc[2][4] = {};

  for (int kh = 0; kh < 2; ++kh) {
    if (kh) __syncthreads();   // all reads of previous half done before overwrite

    // ---- stage K-half kh: 64 rows x 384 k (fp32 gather -> cvt -> LDS) ----
#pragma unroll
    for (int i = 0; i < 3; ++i) {
      const int s    = w + 8 * i;          // 0..23
      const int ks24 = kh * 24 + s;        // global 16-k segment index 0..47
      const int c    = ks24 >> 4;          // channel
      const int ph   = ks24 & 15;          // row within patch
      const float* g = images + ibase + ((size_t)c * 224 + ph) * 224;
      const f32x4 v0 = ((const f32x4*)g)[0];
      const f32x4 v1 = ((const f32x4*)g)[1];
      const f32x4 v2 = ((const f32x4*)g)[2];
      const f32x4 v3 = ((const f32x4*)g)[3];
      __bf16* dst = &As[arow * PITCH + s * 16];
      cvt_store(dst,     v0, v1);
      cvt_store(dst + 8, v2, v3);
    }
    __syncthreads();

    // ---- compute K-half: 12 k-steps, NO barriers; B-frags straight from L2 ----
    const __bf16* wbase = Wb + (size_t)(n0 + ng * 64 + lrow) * 768 + kh * 384 + lq * 8;
#pragma unroll
    for (int ks = 0; ks < 12; ++ks) {
      bf16x8 af[2], bf[4];
#pragma unroll
      for (int i = 0; i < 2; ++i)
        af[i] = *(const bf16x8*)&As[(mg * 32 + i * 16 + lrow) * PITCH + ks * 32 + lq * 8];
#pragma unroll
      for (int j = 0; j < 4; ++j)
        bf[j] = *(const bf16x8*)(wbase + ks * 32 + j * 16 * 768);
#pragma unroll
      for (int i = 0; i < 2; ++i)
#pragma unroll
        for (int j = 0; j < 4; ++j)
          acc[i][j] = __builtin_amdgcn_mfma_f32_16x16x32_bf16(af[i], bf[j], acc[i][j], 0, 0, 0);
    }
  }

  // ---- epilogue: C/D layout col=lane&15, row=(lane>>4)*4+r; scatter past cls ----
#pragma unroll
  for (int j = 0; j < 4; ++j) {
    const int h  = n0 + ng * 64 + j * 16 + lrow;
    const float bv = bias[h];
#pragma unroll
    for (int i = 0; i < 2; ++i) {
      const int mb = m0 + mg * 32 + i * 16 + lq * 4;
#pragma unroll
      for (int r = 0; r < 4; ++r) {
        const int mm  = mb + r;
        const int bb2 = mm / 196, p2 = mm - bb2 * 196;
        out[(size_t)(bb2 * 197 + 1 + p2) * 768 + h] = acc[i][j][r] + bv;
      }
    }
  }
}

extern "C" void kernel_launch(void* const* d_in, const int* in_sizes, int n_in,
                              void* d_out, int out_size, void* d_ws, size_t ws_size,
                              hipStream_t stream) {
  const float* images = (const float*)d_in[0];  // [64,3,224,224]
  const float* Wm     = (const float*)d_in[1];  // [768,768]
  const float* b      = (const float*)d_in[2];  // [768]
  const float* cls    = (const float*)d_in[3];  // [1,768]
  float* out = (float*)d_out;                   // [64,197,768]
  __bf16* Wb = (__bf16*)d_ws;                   // 1.18 MB
  (void)in_sizes; (void)n_in; (void)out_size; (void)ws_size;

  prep_kernel<<<W_BLOCKS + CLS_BLOCKS, 256, 0, stream>>>(Wm, cls, out, Wb);
  gemm_kernel<<<196 * 3, 512, 0, stream>>>(images, Wb, b, out);
}

// Round 6
// 119.322 us; speedup vs baseline: 1.3761x; 1.3761x over previous
//
#include <hip/hip_runtime.h>
#include <cstdint>
#include <cstddef>

// out[64,197,768] = concat(cls, patchify(images[64,3,224,224]) @ W^T + b)
// R6: barrier-free, LDS-free GEMM over FRAGMENT-MAJOR operands.
//   prep: patchify+cvt images -> Af (A fragments, 16m x 32k, [frag][lane][8]),
//         cvt W -> Wf (same frag layout), cls rows -> out.
//   gemm: each wave loads its af/bf fragments straight from L2 as lane-
//         contiguous 1KB loads, register prefetch distance-1, 24 k-steps,
//         ZERO __syncthreads. Grid 1176 (4.6 blocks/CU), XCD-swizzled.
#define MTOT 12544
#define KTOT 768

typedef float  f32x4  __attribute__((ext_vector_type(4)));
typedef __bf16 bf16x8 __attribute__((ext_vector_type(8)));

// ws layout (elements), 4KB pads so distance-1 prefetch may read 1 frag past end
#define AF_ELEMS (784*24*64*8)   // 9,633,792  (19.27 MB)
#define WF_ELEMS (48*24*64*8)    // 589,824    (1.18 MB)
#define PAD_ELEMS 2048

#define PA_BLOCKS 4704   // 784*24*64 threads / 256
#define PW_BLOCKS 288    // 48*24*64 threads / 256
#define CLS_BLOCKS 48    // 64*768/4/256

__global__ __launch_bounds__(256) void prep_kernel(
    const float* __restrict__ images, const float* __restrict__ Wm,
    const float* __restrict__ cls, float* __restrict__ out,
    __bf16* __restrict__ Af, __bf16* __restrict__ Wf) {
  const int bid = blockIdx.x, tid = threadIdx.x;
  if (bid < PA_BLOCKS) {
    const int t = bid * 256 + tid;            // one 8-elem group of one A-frag
    const int l = t & 63, f = t >> 6;
    const int mtile = f / 24, kstep = f - mtile * 24;
    const int m = mtile * 16 + (l & 15);
    const int k = kstep * 32 + (l >> 4) * 8;
    const int bb = m / 196, p = m - bb * 196;
    const int pi = p / 14,  pj = p - pi * 14;
    const int c  = k >> 8,  kr = k & 255;
    const int ph = kr >> 4, pw = kr & 15;     // pw in {0,8}
    const float* g = images +
        ((size_t)((bb * 3 + c) * 224 + pi * 16 + ph)) * 224 + pj * 16 + pw;
    const f32x4 v0 = ((const f32x4*)g)[0];
    const f32x4 v1 = ((const f32x4*)g)[1];
    bf16x8 o;
    o[0]=(__bf16)v0[0]; o[1]=(__bf16)v0[1]; o[2]=(__bf16)v0[2]; o[3]=(__bf16)v0[3];
    o[4]=(__bf16)v1[0]; o[5]=(__bf16)v1[1]; o[6]=(__bf16)v1[2]; o[7]=(__bf16)v1[3];
    *(bf16x8*)(Af + (size_t)t * 8) = o;       // coalesced write
  } else if (bid < PA_BLOCKS + PW_BLOCKS) {
    const int u = (bid - PA_BLOCKS) * 256 + tid;
    const int l = u & 63, f = u >> 6;
    const int ntile = f / 24, kstep = f - ntile * 24;
    const int h = ntile * 16 + (l & 15);
    const int k = kstep * 32 + (l >> 4) * 8;
    const float* g = Wm + (size_t)h * 768 + k;
    const f32x4 v0 = ((const f32x4*)g)[0];
    const f32x4 v1 = ((const f32x4*)g)[1];
    bf16x8 o;
    o[0]=(__bf16)v0[0]; o[1]=(__bf16)v0[1]; o[2]=(__bf16)v0[2]; o[3]=(__bf16)v0[3];
    o[4]=(__bf16)v1[0]; o[5]=(__bf16)v1[1]; o[6]=(__bf16)v1[2]; o[7]=(__bf16)v1[3];
    *(bf16x8*)(Wf + (size_t)u * 8) = o;
  } else {
    const int t  = (bid - PA_BLOCKS - PW_BLOCKS) * 256 + tid;
    const int bb = t / 192;
    const int r  = t - bb * 192;
    *(float4*)(out + (size_t)bb * 197 * 768 + r * 4) = *(const float4*)(cls + r * 4);
  }
}

// ---------------- GEMM: no LDS, no barriers ----------------
#define MFMA __builtin_amdgcn_mfma_f32_16x16x32_bf16

__global__ __launch_bounds__(256, 4) void gemm_kernel(
    const __bf16* __restrict__ Af, const __bf16* __restrict__ Wf,
    const float* __restrict__ bias, float* __restrict__ out) {
  const int tid = threadIdx.x;
  // XCD swizzle: consecutive g on one XCD -> an mblk's 6 n-siblings share L2.
  const int g    = (blockIdx.x & 7) * 147 + (blockIdx.x >> 3);
  const int mblk = g / 6, nblk = g - mblk * 6;
  const int wave = tid >> 6, lane = tid & 63;
  const int mg = wave & 1, ng = wave >> 1;
  const int lrow = lane & 15, lq = lane >> 4;

  // fragment pointers (1 unit = bf16x8 = 16B; frag = 64 units; +64/ks)
  const int mt0 = mblk * 4 + mg * 2;
  const bf16x8* pa0 = (const bf16x8*)Af + (size_t)(mt0    ) * 24 * 64 + lane;
  const bf16x8* pa1 = (const bf16x8*)Af + (size_t)(mt0 + 1) * 24 * 64 + lane;
  const int nt0 = nblk * 8 + ng * 4;
  const bf16x8* pb0 = (const bf16x8*)Wf + (size_t)(nt0    ) * 24 * 64 + lane;
  const bf16x8* pb1 = (const bf16x8*)Wf + (size_t)(nt0 + 1) * 24 * 64 + lane;
  const bf16x8* pb2 = (const bf16x8*)Wf + (size_t)(nt0 + 2) * 24 * 64 + lane;
  const bf16x8* pb3 = (const bf16x8*)Wf + (size_t)(nt0 + 3) * 24 * 64 + lane;

  f32x4 acc[2][4] = {};
  bf16x8 a0 = pa0[0], a1 = pa1[0];
  bf16x8 b0 = pb0[0], b1 = pb1[0], b2 = pb2[0], b3 = pb3[0];

#pragma unroll 4
  for (int ks = 0; ks < 24; ++ks) {
    pa0 += 64; pa1 += 64; pb0 += 64; pb1 += 64; pb2 += 64; pb3 += 64;
    // distance-1 prefetch (reads 1 frag past end on last step -> pads cover it)
    const bf16x8 na0 = pa0[0], na1 = pa1[0];
    const bf16x8 nb0 = pb0[0], nb1 = pb1[0], nb2 = pb2[0], nb3 = pb3[0];
    acc[0][0] = MFMA(a0, b0, acc[0][0], 0, 0, 0);
    acc[0][1] = MFMA(a0, b1, acc[0][1], 0, 0, 0);
    acc[0][2] = MFMA(a0, b2, acc[0][2], 0, 0, 0);
    acc[0][3] = MFMA(a0, b3, acc[0][3], 0, 0, 0);
    acc[1][0] = MFMA(a1, b0, acc[1][0], 0, 0, 0);
    acc[1][1] = MFMA(a1, b1, acc[1][1], 0, 0, 0);
    acc[1][2] = MFMA(a1, b2, acc[1][2], 0, 0, 0);
    acc[1][3] = MFMA(a1, b3, acc[1][3], 0, 0, 0);
    a0 = na0; a1 = na1; b0 = nb0; b1 = nb1; b2 = nb2; b3 = nb3;
  }

  // epilogue: C/D layout col=lane&15 (=n), row=(lane>>4)*4+r (=m); scatter past cls
#pragma unroll
  for (int j = 0; j < 4; ++j) {
    const int h  = (nt0 + j) * 16 + lrow;
    const float bv = bias[h];
#pragma unroll
    for (int i = 0; i < 2; ++i) {
      const int mb = mblk * 64 + mg * 32 + i * 16 + lq * 4;
#pragma unroll
      for (int r = 0; r < 4; ++r) {
        const int mm  = mb + r;
        const int bb2 = mm / 196, p2 = mm - bb2 * 196;
        out[(size_t)(bb2 * 197 + 1 + p2) * 768 + h] = acc[i][j][r] + bv;
      }
    }
  }
}

extern "C" void kernel_launch(void* const* d_in, const int* in_sizes, int n_in,
                              void* d_out, int out_size, void* d_ws, size_t ws_size,
                              hipStream_t stream) {
  const float* images = (const float*)d_in[0];  // [64,3,224,224]
  const float* Wm     = (const float*)d_in[1];  // [768,768]
  const float* b      = (const float*)d_in[2];  // [768]
  const float* cls    = (const float*)d_in[3];  // [1,768]
  float* out = (float*)d_out;                   // [64,197,768]

  __bf16* Af = (__bf16*)d_ws;
  __bf16* Wf = Af + AF_ELEMS + PAD_ELEMS;
  (void)in_sizes; (void)n_in; (void)out_size; (void)ws_size;

  prep_kernel<<<PA_BLOCKS + PW_BLOCKS + CLS_BLOCKS, 256, 0, stream>>>(
      images, Wm, cls, out, Af, Wf);
  gemm_kernel<<<196 * 6, 256, 0, stream>>>(Af, Wf, b, out);
}